// Round 4
// baseline (652.565 us; speedup 1.0000x reference)
//
#include <hip/hip_runtime.h>

// VQ-VAE Vector Quantizer: N=65536 rows, K=4096 codes, D=64, fp32.
// R4: scan blocks 512 threads (8 waves) -> 4 blocks/CU cap gives 32 waves/CU
// (100% occupancy) to hide scalar-load (SMEM) drain latency.
// e-operand via SCALAR path (address_space(4) -> s_load): wave-uniform code k,
// e[k][*] in SGPRs, v_fmac_f32 takes the one-allowed-SGPR operand.
// FMA sequence per (row,code) bit-identical to R2/R3 passing kernels
// (quad-split partials by d mod 4, ascending d, (s0+s1)+(s2+s3),
// dist = fmaf(-2, dot, z2+e2[k]) == (z2+e2[k]) - 2*dot bitwise since 2*dot
// is exact) => identical indices, absmax 0 by construction.
//
// out layout (float): [0,N*D) z_q_st | [ND] vq | [ND+1] cb | [ND+2] cm |
//                     [ND+3, ND+3+N) indices | [ND+3+N] perplexity | [ND+4+N] active

constexpr int N = 65536;
constexpr int K = 4096;
constexpr int D = 64;
constexpr int S = 8;       // K-split
constexpr int KS = K / S;  // 512 codes per slice
constexpr int BT = 512;    // scan block threads (8 waves)

typedef float vf16 __attribute__((ext_vector_type(16)));
typedef const __attribute__((address_space(4))) vf16* cvf16p;
typedef const __attribute__((address_space(4))) float* cfp;

__global__ __launch_bounds__(256) void prep_kernel(const float* __restrict__ emb,
                                                   float* __restrict__ e2,
                                                   int* __restrict__ counts,
                                                   float* __restrict__ loss) {
  int k = blockIdx.x * 256 + threadIdx.x;
  if (k < K) {
    const float4* ep = (const float4*)(emb + (size_t)k * D);
    float s0 = 0.f, s1 = 0.f, s2 = 0.f, s3 = 0.f;
#pragma unroll
    for (int i = 0; i < 16; ++i) {
      float4 e = ep[i];
      s0 = fmaf(e.x, e.x, s0);
      s1 = fmaf(e.y, e.y, s1);
      s2 = fmaf(e.z, e.z, s2);
      s3 = fmaf(e.w, e.w, s3);
    }
    e2[k] = (s0 + s1) + (s2 + s3);
    counts[k] = 0;
  }
  if (blockIdx.x == 0 && threadIdx.x == 0) *loss = 0.0f;
}

// Scan one K-slice for BT rows per block. grid = (N/BT, S). No LDS.
__global__ __launch_bounds__(BT) void vq_scan(const float* __restrict__ z,
                                              const float* __restrict__ emb,
                                              const float* __restrict__ e2,
                                              float* __restrict__ pbest,
                                              int* __restrict__ pidx) {
  const int tid = threadIdx.x;
  const int n = blockIdx.x * BT + tid;
  const int s = blockIdx.y;
  const int k0 = s * KS;

  // This lane's z row in 64 VGPRs.
  float4 zr[16];
  {
    const float4* zp = (const float4*)(z + (size_t)n * D);
#pragma unroll
    for (int i = 0; i < 16; ++i) zr[i] = zp[i];
  }

  // z2, same instruction sequence as R2/R3 (quad-split, ascending d).
  float z2;
  {
    float s0 = 0.f, s1 = 0.f, s2 = 0.f, s3 = 0.f;
#pragma unroll
    for (int i = 0; i < 16; ++i) {
      s0 = fmaf(zr[i].x, zr[i].x, s0);
      s1 = fmaf(zr[i].y, zr[i].y, s1);
      s2 = fmaf(zr[i].z, zr[i].z, s2);
      s3 = fmaf(zr[i].w, zr[i].w, s3);
    }
    z2 = (s0 + s1) + (s2 + s3);
  }

  // Scalar-path pointers (constant address space -> s_load on uniform index).
  cvf16p ep = (cvf16p)(uintptr_t)(emb + (size_t)k0 * D);
  cfp e2p = (cfp)(uintptr_t)(e2 + k0);

  float best = 3.4e38f;
  int bidx = k0;

  for (int k = 0; k < KS; ++k) {
    vf16 ev[4];
#pragma unroll
    for (int c = 0; c < 4; ++c) ev[c] = ep[(size_t)k * 4 + c];

    float s0 = 0.f, s1 = 0.f, s2 = 0.f, s3 = 0.f;
#pragma unroll
    for (int c = 0; c < 4; ++c) {
#pragma unroll
      for (int j = 0; j < 4; ++j) {
        // d = 16*c + 4*j + {0,1,2,3}; partial sN takes d % 4 == N, ascending d
        s0 = fmaf(zr[c * 4 + j].x, ev[c][4 * j + 0], s0);
        s1 = fmaf(zr[c * 4 + j].y, ev[c][4 * j + 1], s1);
        s2 = fmaf(zr[c * 4 + j].z, ev[c][4 * j + 2], s2);
        s3 = fmaf(zr[c * 4 + j].w, ev[c][4 * j + 3], s3);
      }
    }
    float dot = (s0 + s1) + (s2 + s3);
    // == (z2 + e2[k]) - 2.0f*dot bitwise: 2*dot exact, single rounding either way
    float dist = fmaf(-2.0f, dot, z2 + e2p[k]);
    if (dist < best) { best = dist; bidx = k0 + k; }  // strict <: first-index in slice
  }

  pbest[(size_t)s * N + n] = best;
  pidx[(size_t)s * N + n] = bidx;
}

// Combine slices (ascending s = ascending k => first-index tie-break preserved),
// then gather/losses/counts/index write.
__global__ __launch_bounds__(256) void vq_epilogue(const float* __restrict__ z,
                                                   const float* __restrict__ emb,
                                                   const float* __restrict__ pbest,
                                                   const int* __restrict__ pidx,
                                                   float* __restrict__ out,
                                                   int* __restrict__ counts,
                                                   float* __restrict__ loss) {
  __shared__ float red[4];
  const int tid = threadIdx.x;
  const int n = blockIdx.x * 256 + tid;

  float best = pbest[n];
  int bidx = pidx[n];
#pragma unroll
  for (int s = 1; s < S; ++s) {
    float d = pbest[(size_t)s * N + n];
    if (d < best) { best = d; bidx = pidx[(size_t)s * N + n]; }
  }

  out[(size_t)N * D + 3 + n] = (float)bidx;
  atomicAdd(&counts[bidx], 1);

  const float4* zp = (const float4*)(z + (size_t)n * D);
  const float4* qp = (const float4*)(emb + (size_t)bidx * D);
  float4* op = (float4*)(out + (size_t)n * D);
  float lsum = 0.f;
#pragma unroll
  for (int i = 0; i < 16; ++i) {
    float4 q = qp[i];
    float4 zz = zp[i];
    float dx = q.x - zz.x, dy = q.y - zz.y, dz = q.z - zz.z, dw = q.w - zz.w;
    lsum = fmaf(dx, dx, lsum);
    lsum = fmaf(dy, dy, lsum);
    lsum = fmaf(dz, dz, lsum);
    lsum = fmaf(dw, dw, lsum);
    // z_q_st = z + (z_q - z), replicated op-for-op
    float4 r;
    r.x = zz.x + dx; r.y = zz.y + dy; r.z = zz.z + dz; r.w = zz.w + dw;
    op[i] = r;
  }

#pragma unroll
  for (int off = 32; off > 0; off >>= 1) lsum += __shfl_down(lsum, off);
  if ((tid & 63) == 0) red[tid >> 6] = lsum;
  __syncthreads();
  if (tid == 0) atomicAdd(loss, (red[0] + red[1]) + (red[2] + red[3]));
}

__global__ __launch_bounds__(256) void finalize_kernel(const int* __restrict__ counts,
                                                       const float* __restrict__ loss,
                                                       float* __restrict__ out) {
  const int tid = threadIdx.x;
  double ent = 0.0;
  int active = 0;
  for (int k = tid; k < K; k += 256) {
    int c = counts[k];
    float p = (float)c / 65536.0f;
    if (c > 0) active++;
    ent += (double)(p * logf(p + 1e-10f));
  }
#pragma unroll
  for (int off = 32; off > 0; off >>= 1) {
    ent += __shfl_down(ent, off);
    active += __shfl_down(active, off);
  }
  __shared__ double ered[4];
  __shared__ int ared[4];
  if ((tid & 63) == 0) { ered[tid >> 6] = ent; ared[tid >> 6] = active; }
  __syncthreads();
  if (tid == 0) {
    double e = (ered[0] + ered[1]) + (ered[2] + ered[3]);
    int a = (ared[0] + ared[1]) + (ared[2] + ared[3]);
    float mean = *loss / (float)((size_t)N * D);
    float cb = mean;
    float cm = mean;
    float vq = cb + 0.25f * cm;
    size_t base = (size_t)N * D;
    out[base + 0] = vq;
    out[base + 1] = cb;
    out[base + 2] = cm;
    out[base + 3 + N] = (float)exp(-e);
    out[base + 4 + N] = (float)a;
  }
}

extern "C" void kernel_launch(void* const* d_in, const int* in_sizes, int n_in,
                              void* d_out, int out_size, void* d_ws, size_t ws_size,
                              hipStream_t stream) {
  const float* z = (const float*)d_in[0];
  const float* emb = (const float*)d_in[1];
  float* out = (float*)d_out;

  char* w = (char*)d_ws;
  float* e2 = (float*)w;                         w += (size_t)K * sizeof(float);
  int* counts = (int*)w;                         w += (size_t)K * sizeof(int);
  float* loss = (float*)w;                       w += 256;  // keep alignment
  float* pbest = (float*)w;                      w += (size_t)S * N * sizeof(float);
  int* pidx = (int*)w;

  prep_kernel<<<K / 256, 256, 0, stream>>>(emb, e2, counts, loss);
  vq_scan<<<dim3(N / BT, S), BT, 0, stream>>>(z, emb, e2, pbest, pidx);
  vq_epilogue<<<N / 256, 256, 0, stream>>>(z, emb, pbest, pidx, out, counts, loss);
  finalize_kernel<<<1, 256, 0, stream>>>(counts, loss, out);
}

// Round 5
// 634.650 us; speedup vs baseline: 1.0282x; 1.0282x over previous
//
#include <hip/hip_runtime.h>

// VQ-VAE Vector Quantizer: N=65536 rows, K=4096 codes, D=64, fp32.
// R5: e-operand via wave-uniform VMEM loads (all lanes same address -> L1
// broadcast). VMEM returns in-order => compiler emits fine-grained vmcnt(N)
// waits (real pipelining), unlike the scalar path whose out-of-order SMEM
// returns force a full lgkmcnt(0) drain per code (the R3/R4 65% cap).
// 2-buffer chunk rotation keeps e-live at 32 VGPRs; z row (64) + e (32) +
// misc ~= 110 regs -> 4 waves/SIMD retained.
// FMA sequence per (row,code) bit-identical to R2-R4 passing kernels
// (quad-split partials by d mod 4, ascending d, (s0+s1)+(s2+s3),
// dist = fmaf(-2, dot, z2+e2[k])) => identical indices, absmax 0.
//
// out layout (float): [0,N*D) z_q_st | [ND] vq | [ND+1] cb | [ND+2] cm |
//                     [ND+3, ND+3+N) indices | [ND+3+N] perplexity | [ND+4+N] active

constexpr int N = 65536;
constexpr int K = 4096;
constexpr int D = 64;
constexpr int S = 8;       // K-split: grid = (N/256, 8) = 2048 blocks
constexpr int KS = K / S;  // 512 codes per slice

__global__ __launch_bounds__(256) void prep_kernel(const float* __restrict__ emb,
                                                   float* __restrict__ e2,
                                                   int* __restrict__ counts,
                                                   float* __restrict__ loss) {
  int k = blockIdx.x * 256 + threadIdx.x;
  if (k < K) {
    const float4* ep = (const float4*)(emb + (size_t)k * D);
    float s0 = 0.f, s1 = 0.f, s2 = 0.f, s3 = 0.f;
#pragma unroll
    for (int i = 0; i < 16; ++i) {
      float4 e = ep[i];
      s0 = fmaf(e.x, e.x, s0);
      s1 = fmaf(e.y, e.y, s1);
      s2 = fmaf(e.z, e.z, s2);
      s3 = fmaf(e.w, e.w, s3);
    }
    e2[k] = (s0 + s1) + (s2 + s3);
    counts[k] = 0;
  }
  if (blockIdx.x == 0 && threadIdx.x == 0) *loss = 0.0f;
}

#define FMA4(E, Z)                 \
  do {                             \
    s0 = fmaf((Z).x, (E).x, s0);   \
    s1 = fmaf((Z).y, (E).y, s1);   \
    s2 = fmaf((Z).z, (E).z, s2);   \
    s3 = fmaf((Z).w, (E).w, s3);   \
  } while (0)

// Scan one K-slice for 256 rows per block. grid = (N/256, S). No LDS, no SMEM
// in the hot loop — e streams through L1/L2 via uniform-address VMEM.
__global__ __launch_bounds__(256) void vq_scan(const float* __restrict__ z,
                                               const float* __restrict__ emb,
                                               const float* __restrict__ e2,
                                               float* __restrict__ pbest,
                                               int* __restrict__ pidx) {
  const int tid = threadIdx.x;
  const int n = blockIdx.x * 256 + tid;
  const int s = blockIdx.y;
  const int k0 = s * KS;

  // This lane's z row (64 VGPRs, compiler may place in AGPRs — unified file).
  float4 zr[16];
  {
    const float4* zp = (const float4*)(z + (size_t)n * D);
#pragma unroll
    for (int i = 0; i < 16; ++i) zr[i] = zp[i];
  }

  // z2, same instruction sequence as R2-R4 (quad-split, ascending d).
  float z2;
  {
    float s0 = 0.f, s1 = 0.f, s2 = 0.f, s3 = 0.f;
#pragma unroll
    for (int i = 0; i < 16; ++i) {
      s0 = fmaf(zr[i].x, zr[i].x, s0);
      s1 = fmaf(zr[i].y, zr[i].y, s1);
      s2 = fmaf(zr[i].z, zr[i].z, s2);
      s3 = fmaf(zr[i].w, zr[i].w, s3);
    }
    z2 = (s0 + s1) + (s2 + s3);
  }

  const float4* ep = (const float4*)(emb + (size_t)k0 * D);
  const float* e2p = e2 + k0;

  float best = 3.4e38f;
  int bidx = k0;

  for (int k = 0; k < KS; ++k) {
    const float4* row = ep + (size_t)k * 16;
    // Issue first two 16-float chunks + e2 (all wave-uniform VMEM, in-order).
    float4 A0 = row[0], A1 = row[1], A2 = row[2], A3 = row[3];
    float4 B0 = row[4], B1 = row[5], B2 = row[6], B3 = row[7];
    float ek2 = e2p[k];

    float s0 = 0.f, s1 = 0.f, s2 = 0.f, s3 = 0.f;

    // chunk 0 (d 0..15) — B already in flight behind it
    FMA4(A0, zr[0]); FMA4(A1, zr[1]); FMA4(A2, zr[2]); FMA4(A3, zr[3]);
    // refill A with chunk 2 while chunk 1 computes
    A0 = row[8]; A1 = row[9]; A2 = row[10]; A3 = row[11];
    // chunk 1 (d 16..31)
    FMA4(B0, zr[4]); FMA4(B1, zr[5]); FMA4(B2, zr[6]); FMA4(B3, zr[7]);
    // refill B with chunk 3
    B0 = row[12]; B1 = row[13]; B2 = row[14]; B3 = row[15];
    // chunk 2 (d 32..47)
    FMA4(A0, zr[8]); FMA4(A1, zr[9]); FMA4(A2, zr[10]); FMA4(A3, zr[11]);
    // chunk 3 (d 48..63)
    FMA4(B0, zr[12]); FMA4(B1, zr[13]); FMA4(B2, zr[14]); FMA4(B3, zr[15]);

    float dot = (s0 + s1) + (s2 + s3);
    // == (z2 + e2[k]) - 2.0f*dot bitwise (2*dot exact, single rounding)
    float dist = fmaf(-2.0f, dot, z2 + ek2);
    if (dist < best) { best = dist; bidx = k0 + k; }  // strict <: first-index
  }

  pbest[(size_t)s * N + n] = best;
  pidx[(size_t)s * N + n] = bidx;
}

// Combine slices (ascending s = ascending k => first-index tie-break preserved),
// then gather/losses/counts/index write.
__global__ __launch_bounds__(256) void vq_epilogue(const float* __restrict__ z,
                                                   const float* __restrict__ emb,
                                                   const float* __restrict__ pbest,
                                                   const int* __restrict__ pidx,
                                                   float* __restrict__ out,
                                                   int* __restrict__ counts,
                                                   float* __restrict__ loss) {
  __shared__ float red[4];
  const int tid = threadIdx.x;
  const int n = blockIdx.x * 256 + tid;

  float best = pbest[n];
  int bidx = pidx[n];
#pragma unroll
  for (int s = 1; s < S; ++s) {
    float d = pbest[(size_t)s * N + n];
    if (d < best) { best = d; bidx = pidx[(size_t)s * N + n]; }
  }

  out[(size_t)N * D + 3 + n] = (float)bidx;
  atomicAdd(&counts[bidx], 1);

  const float4* zp = (const float4*)(z + (size_t)n * D);
  const float4* qp = (const float4*)(emb + (size_t)bidx * D);
  float4* op = (float4*)(out + (size_t)n * D);
  float lsum = 0.f;
#pragma unroll
  for (int i = 0; i < 16; ++i) {
    float4 q = qp[i];
    float4 zz = zp[i];
    float dx = q.x - zz.x, dy = q.y - zz.y, dz = q.z - zz.z, dw = q.w - zz.w;
    lsum = fmaf(dx, dx, lsum);
    lsum = fmaf(dy, dy, lsum);
    lsum = fmaf(dz, dz, lsum);
    lsum = fmaf(dw, dw, lsum);
    // z_q_st = z + (z_q - z), replicated op-for-op
    float4 r;
    r.x = zz.x + dx; r.y = zz.y + dy; r.z = zz.z + dz; r.w = zz.w + dw;
    op[i] = r;
  }

#pragma unroll
  for (int off = 32; off > 0; off >>= 1) lsum += __shfl_down(lsum, off);
  if ((tid & 63) == 0) red[tid >> 6] = lsum;
  __syncthreads();
  if (tid == 0) atomicAdd(loss, (red[0] + red[1]) + (red[2] + red[3]));
}

__global__ __launch_bounds__(256) void finalize_kernel(const int* __restrict__ counts,
                                                       const float* __restrict__ loss,
                                                       float* __restrict__ out) {
  const int tid = threadIdx.x;
  double ent = 0.0;
  int active = 0;
  for (int k = tid; k < K; k += 256) {
    int c = counts[k];
    float p = (float)c / 65536.0f;
    if (c > 0) active++;
    ent += (double)(p * logf(p + 1e-10f));
  }
#pragma unroll
  for (int off = 32; off > 0; off >>= 1) {
    ent += __shfl_down(ent, off);
    active += __shfl_down(active, off);
  }
  __shared__ double ered[4];
  __shared__ int ared[4];
  if ((tid & 63) == 0) { ered[tid >> 6] = ent; ared[tid >> 6] = active; }
  __syncthreads();
  if (tid == 0) {
    double e = (ered[0] + ered[1]) + (ered[2] + ered[3]);
    int a = (ared[0] + ared[1]) + (ared[2] + ared[3]);
    float mean = *loss / (float)((size_t)N * D);
    float cb = mean;
    float cm = mean;
    float vq = cb + 0.25f * cm;
    size_t base = (size_t)N * D;
    out[base + 0] = vq;
    out[base + 1] = cb;
    out[base + 2] = cm;
    out[base + 3 + N] = (float)exp(-e);
    out[base + 4 + N] = (float)a;
  }
}

extern "C" void kernel_launch(void* const* d_in, const int* in_sizes, int n_in,
                              void* d_out, int out_size, void* d_ws, size_t ws_size,
                              hipStream_t stream) {
  const float* z = (const float*)d_in[0];
  const float* emb = (const float*)d_in[1];
  float* out = (float*)d_out;

  char* w = (char*)d_ws;
  float* e2 = (float*)w;                         w += (size_t)K * sizeof(float);
  int* counts = (int*)w;                         w += (size_t)K * sizeof(int);
  float* loss = (float*)w;                       w += 256;  // keep alignment
  float* pbest = (float*)w;                      w += (size_t)S * N * sizeof(float);
  int* pidx = (int*)w;

  prep_kernel<<<K / 256, 256, 0, stream>>>(emb, e2, counts, loss);
  vq_scan<<<dim3(N / 256, S), 256, 0, stream>>>(z, emb, e2, pbest, pidx);
  vq_epilogue<<<N / 256, 256, 0, stream>>>(z, emb, pbest, pidx, out, counts, loss);
  finalize_kernel<<<1, 256, 0, stream>>>(counts, loss, out);
}

// Round 6
// 588.967 us; speedup vs baseline: 1.1080x; 1.0776x over previous
//
#include <hip/hip_runtime.h>

// VQ-VAE Vector Quantizer: N=65536 rows, K=4096 codes, D=64, fp32.
// R6: 2 rows per thread on the scalar-e path. The per-code lgkmcnt(0) drain
// (SMEM is out-of-order; partial waits illegal) is amortized over 2 rows'
// FMA work (~276 issue-cyc per drain instead of ~138), and e-row SMEM
// traffic halves. 2 waves/SIMD alternate: each wave's ~150cyc drain hides
// under the other's compute burst. __launch_bounds__(256,2) gives the
// allocator room to keep both z-rows in arch VGPRs (no AGPR bouncing).
// Per-row FMA chains bit-identical to R2-R5 passing kernels (quad-split
// partials by d mod 4, ascending d, (s0+s1)+(s2+s3),
// dist = fmaf(-2, dot, z2+e2[k])) => identical indices, absmax 0.
//
// out layout (float): [0,N*D) z_q_st | [ND] vq | [ND+1] cb | [ND+2] cm |
//                     [ND+3, ND+3+N) indices | [ND+3+N] perplexity | [ND+4+N] active

constexpr int N = 65536;
constexpr int K = 4096;
constexpr int D = 64;
constexpr int S = 4;       // K-split: grid = (N/512, 4) = 512 blocks = 2/CU exactly
constexpr int KS = K / S;  // 1024 codes per slice

typedef float vf16 __attribute__((ext_vector_type(16)));
typedef const __attribute__((address_space(4))) vf16* cvf16p;
typedef const __attribute__((address_space(4))) float* cfp;

__global__ __launch_bounds__(256) void prep_kernel(const float* __restrict__ emb,
                                                   float* __restrict__ e2,
                                                   int* __restrict__ counts,
                                                   float* __restrict__ loss) {
  int k = blockIdx.x * 256 + threadIdx.x;
  if (k < K) {
    const float4* ep = (const float4*)(emb + (size_t)k * D);
    float s0 = 0.f, s1 = 0.f, s2 = 0.f, s3 = 0.f;
#pragma unroll
    for (int i = 0; i < 16; ++i) {
      float4 e = ep[i];
      s0 = fmaf(e.x, e.x, s0);
      s1 = fmaf(e.y, e.y, s1);
      s2 = fmaf(e.z, e.z, s2);
      s3 = fmaf(e.w, e.w, s3);
    }
    e2[k] = (s0 + s1) + (s2 + s3);
    counts[k] = 0;
  }
  if (blockIdx.x == 0 && threadIdx.x == 0) *loss = 0.0f;
}

// Scan one K-slice, 2 rows per thread (rows base+tid and base+256+tid).
// grid = (N/512, S). No LDS; e streams through the scalar path (SGPRs).
__global__ __launch_bounds__(256, 2) void vq_scan(const float* __restrict__ z,
                                                  const float* __restrict__ emb,
                                                  const float* __restrict__ e2,
                                                  float* __restrict__ pbest,
                                                  int* __restrict__ pidx) {
  const int tid = threadIdx.x;
  const int na = blockIdx.x * 512 + tid;        // row A
  const int nb = na + 256;                      // row B
  const int s = blockIdx.y;
  const int k0 = s * KS;

  // Two z rows in arch VGPRs (128 floats).
  float4 zra[16], zrb[16];
  {
    const float4* zpa = (const float4*)(z + (size_t)na * D);
    const float4* zpb = (const float4*)(z + (size_t)nb * D);
#pragma unroll
    for (int i = 0; i < 16; ++i) { zra[i] = zpa[i]; zrb[i] = zpb[i]; }
  }

  // z2 per row, same instruction sequence as R2-R5 (quad-split, ascending d).
  float z2a, z2b;
  {
    float a0 = 0.f, a1 = 0.f, a2 = 0.f, a3 = 0.f;
    float b0 = 0.f, b1 = 0.f, b2 = 0.f, b3 = 0.f;
#pragma unroll
    for (int i = 0; i < 16; ++i) {
      a0 = fmaf(zra[i].x, zra[i].x, a0);
      a1 = fmaf(zra[i].y, zra[i].y, a1);
      a2 = fmaf(zra[i].z, zra[i].z, a2);
      a3 = fmaf(zra[i].w, zra[i].w, a3);
      b0 = fmaf(zrb[i].x, zrb[i].x, b0);
      b1 = fmaf(zrb[i].y, zrb[i].y, b1);
      b2 = fmaf(zrb[i].z, zrb[i].z, b2);
      b3 = fmaf(zrb[i].w, zrb[i].w, b3);
    }
    z2a = (a0 + a1) + (a2 + a3);
    z2b = (b0 + b1) + (b2 + b3);
  }

  // Scalar-path pointers (constant address space -> s_load on uniform index).
  cvf16p ep = (cvf16p)(uintptr_t)(emb + (size_t)k0 * D);
  cfp e2p = (cfp)(uintptr_t)(e2 + k0);

  float besta = 3.4e38f, bestb = 3.4e38f;
  int bidxa = k0, bidxb = k0;

  for (int k = 0; k < KS; ++k) {
    // e[k][0:64] -> 4x s_load_dwordx16 into SGPRs (wave-uniform), + e2.
    vf16 ev[4];
#pragma unroll
    for (int c = 0; c < 4; ++c) ev[c] = ep[(size_t)k * 4 + c];
    float ek2 = e2p[k];

    float a0 = 0.f, a1 = 0.f, a2 = 0.f, a3 = 0.f;
    float b0 = 0.f, b1 = 0.f, b2 = 0.f, b3 = 0.f;
#pragma unroll
    for (int c = 0; c < 4; ++c) {
#pragma unroll
      for (int j = 0; j < 4; ++j) {
        // d = 16*c + 4*j + {0,1,2,3}; per-row chain sN takes d%4==N, ascending d
        float e0 = ev[c][4 * j + 0], e1 = ev[c][4 * j + 1];
        float e2v = ev[c][4 * j + 2], e3 = ev[c][4 * j + 3];
        a0 = fmaf(zra[c * 4 + j].x, e0, a0);
        a1 = fmaf(zra[c * 4 + j].y, e1, a1);
        a2 = fmaf(zra[c * 4 + j].z, e2v, a2);
        a3 = fmaf(zra[c * 4 + j].w, e3, a3);
        b0 = fmaf(zrb[c * 4 + j].x, e0, b0);
        b1 = fmaf(zrb[c * 4 + j].y, e1, b1);
        b2 = fmaf(zrb[c * 4 + j].z, e2v, b2);
        b3 = fmaf(zrb[c * 4 + j].w, e3, b3);
      }
    }
    float dota = (a0 + a1) + (a2 + a3);
    float dotb = (b0 + b1) + (b2 + b3);
    // == (z2 + e2[k]) - 2.0f*dot bitwise (2*dot exact, single rounding)
    float dista = fmaf(-2.0f, dota, z2a + ek2);
    float distb = fmaf(-2.0f, dotb, z2b + ek2);
    int kk = k0 + k;
    if (dista < besta) { besta = dista; bidxa = kk; }  // strict <: first-index
    if (distb < bestb) { bestb = distb; bidxb = kk; }
  }

  pbest[(size_t)s * N + na] = besta;
  pidx[(size_t)s * N + na] = bidxa;
  pbest[(size_t)s * N + nb] = bestb;
  pidx[(size_t)s * N + nb] = bidxb;
}

// Combine slices (ascending s = ascending k => first-index tie-break preserved),
// then gather/losses/counts/index write.
__global__ __launch_bounds__(256) void vq_epilogue(const float* __restrict__ z,
                                                   const float* __restrict__ emb,
                                                   const float* __restrict__ pbest,
                                                   const int* __restrict__ pidx,
                                                   float* __restrict__ out,
                                                   int* __restrict__ counts,
                                                   float* __restrict__ loss) {
  __shared__ float red[4];
  const int tid = threadIdx.x;
  const int n = blockIdx.x * 256 + tid;

  float best = pbest[n];
  int bidx = pidx[n];
#pragma unroll
  for (int s = 1; s < S; ++s) {
    float d = pbest[(size_t)s * N + n];
    if (d < best) { best = d; bidx = pidx[(size_t)s * N + n]; }
  }

  out[(size_t)N * D + 3 + n] = (float)bidx;
  atomicAdd(&counts[bidx], 1);

  const float4* zp = (const float4*)(z + (size_t)n * D);
  const float4* qp = (const float4*)(emb + (size_t)bidx * D);
  float4* op = (float4*)(out + (size_t)n * D);
  float lsum = 0.f;
#pragma unroll
  for (int i = 0; i < 16; ++i) {
    float4 q = qp[i];
    float4 zz = zp[i];
    float dx = q.x - zz.x, dy = q.y - zz.y, dz = q.z - zz.z, dw = q.w - zz.w;
    lsum = fmaf(dx, dx, lsum);
    lsum = fmaf(dy, dy, lsum);
    lsum = fmaf(dz, dz, lsum);
    lsum = fmaf(dw, dw, lsum);
    // z_q_st = z + (z_q - z), replicated op-for-op
    float4 r;
    r.x = zz.x + dx; r.y = zz.y + dy; r.z = zz.z + dz; r.w = zz.w + dw;
    op[i] = r;
  }

#pragma unroll
  for (int off = 32; off > 0; off >>= 1) lsum += __shfl_down(lsum, off);
  if ((tid & 63) == 0) red[tid >> 6] = lsum;
  __syncthreads();
  if (tid == 0) atomicAdd(loss, (red[0] + red[1]) + (red[2] + red[3]));
}

__global__ __launch_bounds__(256) void finalize_kernel(const int* __restrict__ counts,
                                                       const float* __restrict__ loss,
                                                       float* __restrict__ out) {
  const int tid = threadIdx.x;
  double ent = 0.0;
  int active = 0;
  for (int k = tid; k < K; k += 256) {
    int c = counts[k];
    float p = (float)c / 65536.0f;
    if (c > 0) active++;
    ent += (double)(p * logf(p + 1e-10f));
  }
#pragma unroll
  for (int off = 32; off > 0; off >>= 1) {
    ent += __shfl_down(ent, off);
    active += __shfl_down(active, off);
  }
  __shared__ double ered[4];
  __shared__ int ared[4];
  if ((tid & 63) == 0) { ered[tid >> 6] = ent; ared[tid >> 6] = active; }
  __syncthreads();
  if (tid == 0) {
    double e = (ered[0] + ered[1]) + (ered[2] + ered[3]);
    int a = (ared[0] + ared[1]) + (ared[2] + ared[3]);
    float mean = *loss / (float)((size_t)N * D);
    float cb = mean;
    float cm = mean;
    float vq = cb + 0.25f * cm;
    size_t base = (size_t)N * D;
    out[base + 0] = vq;
    out[base + 1] = cb;
    out[base + 2] = cm;
    out[base + 3 + N] = (float)exp(-e);
    out[base + 4 + N] = (float)a;
  }
}

extern "C" void kernel_launch(void* const* d_in, const int* in_sizes, int n_in,
                              void* d_out, int out_size, void* d_ws, size_t ws_size,
                              hipStream_t stream) {
  const float* z = (const float*)d_in[0];
  const float* emb = (const float*)d_in[1];
  float* out = (float*)d_out;

  char* w = (char*)d_ws;
  float* e2 = (float*)w;                         w += (size_t)K * sizeof(float);
  int* counts = (int*)w;                         w += (size_t)K * sizeof(int);
  float* loss = (float*)w;                       w += 256;  // keep alignment
  float* pbest = (float*)w;                      w += (size_t)S * N * sizeof(float);
  int* pidx = (int*)w;

  prep_kernel<<<K / 256, 256, 0, stream>>>(emb, e2, counts, loss);
  vq_scan<<<dim3(N / 512, S), 256, 0, stream>>>(z, emb, e2, pbest, pidx);
  vq_epilogue<<<N / 256, 256, 0, stream>>>(z, emb, pbest, pidx, out, counts, loss);
  finalize_kernel<<<1, 256, 0, stream>>>(counts, loss, out);
}